// Round 5
// baseline (838.907 us; speedup 1.0000x reference)
//
#include <hip/hip_runtime.h>
#include <stdint.h>

#define B_ 4
#define S_ 2048
#define D_ 2048
#define H_ 2560
#define O_ 2048
#define M_ (B_*S_)   // 8192 rows
#define NCH 64       // scan S-chunks
#define LCH (S_/NCH) // 32

typedef __attribute__((ext_vector_type(8))) short bf16x8;
typedef __attribute__((ext_vector_type(4))) float f32x4;

typedef const __attribute__((address_space(1))) unsigned int* gp32;
typedef __attribute__((address_space(3))) unsigned int* lp32;

__device__ __forceinline__ void async_cp16(const unsigned short* g, unsigned short* l) {
    __builtin_amdgcn_global_load_lds((gp32)g, (lp32)l, 16, 0, 0);
}

__device__ __forceinline__ unsigned short f2bf(float f) {
    unsigned int x = __float_as_uint(f);
    x += 0x7fffu + ((x >> 16) & 1u);   // round-to-nearest-even
    return (unsigned short)(x >> 16);
}
__device__ __forceinline__ float bf2f(unsigned short s) {
    return __uint_as_float(((unsigned int)s) << 16);
}
__device__ __forceinline__ float4 ld_bf4(const unsigned short* p) {
    const uint2 u = *(const uint2*)p;
    float4 r;
    r.x = bf2f((unsigned short)(u.x & 0xffffu));
    r.y = bf2f((unsigned short)(u.x >> 16));
    r.z = bf2f((unsigned short)(u.y & 0xffffu));
    r.w = bf2f((unsigned short)(u.y >> 16));
    return r;
}
__device__ __forceinline__ uint2 st_bf4(float a, float b, float c, float d) {
    union { unsigned short s[4]; uint2 u; } pk;
    pk.s[0] = f2bf(a); pk.s[1] = f2bf(b); pk.s[2] = f2bf(c); pk.s[3] = f2bf(d);
    return pk.u;
}
__device__ __forceinline__ float fast_sigmoid(float x) { return 1.0f / (1.0f + __expf(-x)); }
__device__ __forceinline__ float gelu_tanh(float x) {
    // jax.nn.gelu approximate=True
    float t = 0.7978845608028654f * (x + 0.044715f * x * x * x);
    float e = __expf(2.0f * t);
    float th = 1.0f - 2.0f / (e + 1.0f);
    return 0.5f * x * (1.0f + th);
}

// ---------------- cast x fp32 -> bf16 ----------------
__global__ void cast_x_kernel(const float* __restrict__ in, unsigned short* __restrict__ out, int n4) {
    int gid = blockIdx.x * 256 + threadIdx.x;
    if (gid >= n4) return;
    const float4 v = ((const float4*)in)[gid];
    ((uint2*)out)[gid] = st_bf4(v.x, v.y, v.z, v.w);
}

// ---------------- merged transpose+cast: 5 weights in one launch ----------------
// z=0: Wl[D,H]->WlrT ; z=1: Wr[D,H]->WlrT+H*D ; z=2: Wa[H,H]->WaiT ;
// z=3: Wi[H,H]->WaiT+H*H ; z=4: Wo[H,O]->WoT. in [K,N] fp32 -> out [N,K] bf16.
__global__ void transpose_all_kernel(const float* __restrict__ Wl, const float* __restrict__ Wr,
                                     const float* __restrict__ Wa, const float* __restrict__ Wi,
                                     const float* __restrict__ Wo,
                                     unsigned short* __restrict__ WlrT,
                                     unsigned short* __restrict__ WaiT,
                                     unsigned short* __restrict__ WoT) {
    __shared__ float tile[64][65];
    const float* src; unsigned short* dst; int K, N;
    switch (blockIdx.z) {
        case 0:  src = Wl; dst = WlrT;                       K = D_; N = H_; break;
        case 1:  src = Wr; dst = WlrT + (size_t)H_ * D_;     K = D_; N = H_; break;
        case 2:  src = Wa; dst = WaiT;                       K = H_; N = H_; break;
        case 3:  src = Wi; dst = WaiT + (size_t)H_ * H_;     K = H_; N = H_; break;
        default: src = Wo; dst = WoT;                        K = H_; N = O_; break;
    }
    const int k0 = blockIdx.y * 64, n0 = blockIdx.x * 64;
    if (k0 >= K || n0 >= N) return;   // block-uniform early exit (before barrier)
    const int t = threadIdx.x;
    const int r = t >> 4, c4 = (t & 15) * 4;
    #pragma unroll
    for (int p = 0; p < 4; ++p) {
        const float4 v = *(const float4*)(src + (size_t)(k0 + p*16 + r) * N + n0 + c4);
        tile[p*16 + r][c4+0] = v.x;
        tile[p*16 + r][c4+1] = v.y;
        tile[p*16 + r][c4+2] = v.z;
        tile[p*16 + r][c4+3] = v.w;
    }
    __syncthreads();
    #pragma unroll
    for (int p = 0; p < 4; ++p) {
        const int nn = n0 + p*16 + r;
        *(uint2*)(dst + (size_t)nn * K + k0 + c4) =
            st_bf4(tile[c4+0][p*16 + r], tile[c4+1][p*16 + r],
                   tile[c4+2][p*16 + r], tile[c4+3][p*16 + r]);
    }
}

// ---------------- bf16 MFMA GEMM, 128x128 tile, BK=64, XOR-swizzled LDS ----------------
// Proven structure: 219us / 45-46% MfmaUtil on the big GEMMs; 32KB LDS ->
// 3-4 blocks/CU whose mutual drift covers the per-K-step barrier drain
// (m114 mechanism). 8-phase 256^2 ports were tried 3x and never beat this.
// MODE 0: N=5120: n<H -> left=bf16(gelu(v+b0[n])); n>=H -> rin=bf16(v+b1[n-H])
// MODE 1: N=5120: n<H -> r=bf16(sigmoid(v+b0[n])); n>=H -> i=bf16(sigmoid(v+b1[n-H]))
// MODE 2: N=2048: out=fp32(v+b0[n])
template <int MODE>
__global__ __launch_bounds__(256, 4) void gemm_kernel(
        const unsigned short* __restrict__ A,
        const unsigned short* __restrict__ Bt,
        const int K,
        const float* __restrict__ bias0,
        const float* __restrict__ bias1,
        void* __restrict__ out0,
        void* __restrict__ out1)
{
    __shared__ __align__(16) unsigned short As[128*64];
    __shared__ __align__(16) unsigned short Bs[128*64];
    const int t = threadIdx.x;
    const int m0 = blockIdx.y * 128;
    const int n0 = blockIdx.x * 128;

    // staging: thread t covers rows {t>>3 + 32j}, k-chunk (t&7)^(row&7)
    const int srow = t >> 3;                         // 0..31
    const int csrc = ((t & 7) ^ (srow & 7)) * 8;     // element offset in row
    const unsigned short* gA = A  + (size_t)(m0 + srow) * K + csrc;
    const unsigned short* gB = Bt + (size_t)(n0 + srow) * K + csrc;
    unsigned short* lA = As + t * 8;                 // + j*2048 halfwords per call
    unsigned short* lB = Bs + t * 8;
    const size_t gstep = (size_t)32 * K;

    const int lane = t & 63;
    const int w = t >> 6;
    const int wm = (w >> 1) * 64;
    const int wn = (w & 1) * 64;
    const int q = lane >> 4;        // k-quad 0..3
    const int l16 = lane & 15;

    f32x4 acc[4][4];
    #pragma unroll
    for (int i = 0; i < 4; ++i)
        #pragma unroll
        for (int j = 0; j < 4; ++j)
            acc[i][j] = (f32x4){0.f, 0.f, 0.f, 0.f};

    for (int k0 = 0; k0 < K; k0 += 64) {
        #pragma unroll
        for (int j = 0; j < 4; ++j) {
            async_cp16(gA + j * gstep, lA + j * 2048);
            async_cp16(gB + j * gstep, lB + j * 2048);
        }
        gA += 64; gB += 64;
        __syncthreads();   // drains vmcnt for global_load_lds
        #pragma unroll
        for (int ks = 0; ks < 2; ++ks) {
            const int ch = ((q + ks * 4) ^ (l16 & 7)) * 8;   // swizzled chunk offset
            bf16x8 af[4], bfr[4];
            #pragma unroll
            for (int f = 0; f < 4; ++f)
                af[f]  = *(const bf16x8*)(As + (wm + f*16 + l16) * 64 + ch);
            #pragma unroll
            for (int f = 0; f < 4; ++f)
                bfr[f] = *(const bf16x8*)(Bs + (wn + f*16 + l16) * 64 + ch);
            #pragma unroll
            for (int fm = 0; fm < 4; ++fm)
                #pragma unroll
                for (int fn = 0; fn < 4; ++fn)
                    acc[fm][fn] = __builtin_amdgcn_mfma_f32_16x16x32_bf16(af[fm], bfr[fn], acc[fm][fn], 0, 0, 0);
        }
        __syncthreads();
    }

    const int rbase = q * 4;   // C/D: col=lane&15, row=(lane>>4)*4+reg
    #pragma unroll
    for (int fm = 0; fm < 4; ++fm) {
        #pragma unroll
        for (int fn = 0; fn < 4; ++fn) {
            const int cc = n0 + wn + fn * 16 + l16;
            #pragma unroll
            for (int j = 0; j < 4; ++j) {
                const int rr = m0 + wm + fm * 16 + rbase + j;
                float v = acc[fm][fn][j];
                if (MODE == 0) {
                    if (cc < H_) {
                        ((unsigned short*)out0)[(size_t)rr * H_ + cc] = f2bf(gelu_tanh(v + bias0[cc]));
                    } else {
                        const int c2 = cc - H_;
                        ((unsigned short*)out1)[(size_t)rr * H_ + c2] = f2bf(v + bias1[c2]);
                    }
                } else if (MODE == 1) {
                    if (cc < H_) {
                        ((unsigned short*)out0)[(size_t)rr * H_ + cc] = f2bf(fast_sigmoid(v + bias0[cc]));
                    } else {
                        const int c2 = cc - H_;
                        ((unsigned short*)out1)[(size_t)rr * H_ + c2] = f2bf(fast_sigmoid(v + bias1[c2]));
                    }
                } else {
                    ((float*)out0)[(size_t)rr * O_ + cc] = v + bias0[cc];
                }
            }
        }
    }
}

// ---------------- causal depthwise conv (width 4), bf16 in -> bf16 out ----------------
__global__ void conv_kernel(const unsigned short* __restrict__ rin,
                            const float* __restrict__ cw,
                            const float* __restrict__ cb,
                            unsigned short* __restrict__ ub)
{
    const int gid = blockIdx.x * 256 + threadIdx.x;   // (b, s/4, h/4)
    const int h = (gid % (H_/4)) * 4;
    const int tmp = gid / (H_/4);
    const int s0 = (tmp % (S_/4)) * 4;
    const int b = tmp / (S_/4);
    const unsigned short* base = rin + (size_t)b * S_ * H_ + h;
    float4 rows[7];
    #pragma unroll
    for (int idx = 0; idx < 7; ++idx) {
        const int s = s0 - 3 + idx;
        if (s >= 0) rows[idx] = ld_bf4(base + (size_t)s * H_);
        else        rows[idx] = make_float4(0.f, 0.f, 0.f, 0.f);
    }
    float4 w[4];
    #pragma unroll
    for (int j = 0; j < 4; ++j) w[j] = *(const float4*)(cw + j * H_ + h);
    const float4 bias = *(const float4*)(cb + h);
    #pragma unroll
    for (int p = 0; p < 4; ++p) {
        float ox = bias.x, oy = bias.y, oz = bias.z, ow = bias.w;
        #pragma unroll
        for (int j = 0; j < 4; ++j) {
            ox += w[j].x * rows[p + j].x;
            oy += w[j].y * rows[p + j].y;
            oz += w[j].z * rows[p + j].z;
            ow += w[j].w * rows[p + j].w;
        }
        const size_t oidx = (size_t)b * S_ * H_ + (size_t)(s0 + p) * H_ + h;
        *(uint2*)(ub + oidx) = st_bf4(ox, oy, oz, ow);
    }
}

// ---------------- chunked RG-LRU scan (3 passes, x4-vectorized, NCH=64) ----------------
// Each thread owns 4 consecutive h-channels: all loads are 8B uint2 (4x bf16),
// all state is float4 (G13: scalar bf16 loads cost ~2x on memory-bound kernels).
__global__ void scan_pass1(const unsigned short* __restrict__ rg,
                           const unsigned short* __restrict__ ig,
                           const unsigned short* __restrict__ ub,
                           const float* __restrict__ lam,
                           float* __restrict__ Asum,
                           float* __restrict__ Hend)
{
    const int tid = blockIdx.x * 256 + threadIdx.x;  // (b*NCH + c)*(H/4) + h4
    const int h4 = (tid % (H_/4)) * 4;
    const int t2 = tid / (H_/4);
    const int c = t2 % NCH;
    const int b = t2 / NCH;
    const float4 lm = *(const float4*)(lam + h4);
    float kh[4];
    kh[0] = -8.0f * log1pf(__expf(-lm.x));
    kh[1] = -8.0f * log1pf(__expf(-lm.y));
    kh[2] = -8.0f * log1pf(__expf(-lm.z));
    kh[3] = -8.0f * log1pf(__expf(-lm.w));
    size_t idx = ((size_t)b * S_ + (size_t)c * LCH) * H_ + h4;
    float A[4] = {1.f, 1.f, 1.f, 1.f};
    float hs[4] = {0.f, 0.f, 0.f, 0.f};
    #pragma unroll 4
    for (int s = 0; s < LCH; ++s, idx += H_) {
        const float4 rv = ld_bf4(rg + idx);
        const float4 iv = ld_bf4(ig + idx);
        const float4 uv = ld_bf4(ub + idx);
        const float rr[4] = {rv.x, rv.y, rv.z, rv.w};
        const float ii[4] = {iv.x, iv.y, iv.z, iv.w};
        const float uu[4] = {uv.x, uv.y, uv.z, uv.w};
        #pragma unroll
        for (int j = 0; j < 4; ++j) {
            const float a = __expf(kh[j] * rr[j]);
            const float beta = sqrtf(fmaxf(1.f - a * a, 1e-12f));
            hs[j] = a * hs[j] + beta * ii[j] * uu[j];
            A[j] *= a;
        }
    }
    const size_t o = ((size_t)b * NCH + c) * H_ + h4;
    *(float4*)(Asum + o) = make_float4(A[0], A[1], A[2], A[3]);
    *(float4*)(Hend + o) = make_float4(hs[0], hs[1], hs[2], hs[3]);
}

__global__ void scan_pass2(const float* __restrict__ Asum, float* __restrict__ Hend, int n) {
    const int tid = blockIdx.x * 256 + threadIdx.x;   // b*(H/4) + h4idx
    if (tid >= n) return;                             // grid is ceil(n/256)
    const int h4 = (tid % (H_/4)) * 4;
    const int b = tid / (H_/4);
    float4 hin = make_float4(0.f, 0.f, 0.f, 0.f);
    #pragma unroll 8
    for (int c = 0; c < NCH; ++c) {
        const size_t q = ((size_t)b * NCH + c) * H_ + h4;
        const float4 Ac = *(const float4*)(Asum + q);
        const float4 he = *(const float4*)(Hend + q);
        *(float4*)(Hend + q) = hin;
        hin.x = he.x + Ac.x * hin.x;
        hin.y = he.y + Ac.y * hin.y;
        hin.z = he.z + Ac.z * hin.z;
        hin.w = he.w + Ac.w * hin.w;
    }
}

__global__ void scan_pass3(const unsigned short* __restrict__ rg,
                           const unsigned short* __restrict__ ig,
                           const unsigned short* __restrict__ ub,
                           const unsigned short* __restrict__ leftb,
                           const float* __restrict__ lam,
                           const float* __restrict__ Hin,
                           unsigned short* __restrict__ lrb)
{
    const int tid = blockIdx.x * 256 + threadIdx.x;
    const int h4 = (tid % (H_/4)) * 4;
    const int t2 = tid / (H_/4);
    const int c = t2 % NCH;
    const int b = t2 / NCH;
    const float4 lm = *(const float4*)(lam + h4);
    float kh[4];
    kh[0] = -8.0f * log1pf(__expf(-lm.x));
    kh[1] = -8.0f * log1pf(__expf(-lm.y));
    kh[2] = -8.0f * log1pf(__expf(-lm.z));
    kh[3] = -8.0f * log1pf(__expf(-lm.w));
    size_t idx = ((size_t)b * S_ + (size_t)c * LCH) * H_ + h4;
    const size_t o = ((size_t)b * NCH + c) * H_ + h4;
    const float4 h0 = *(const float4*)(Hin + o);
    float hs[4] = {h0.x, h0.y, h0.z, h0.w};
    #pragma unroll 4
    for (int s = 0; s < LCH; ++s, idx += H_) {
        const float4 rv = ld_bf4(rg + idx);
        const float4 iv = ld_bf4(ig + idx);
        const float4 uv = ld_bf4(ub + idx);
        const float4 lf = ld_bf4(leftb + idx);
        const float rr[4] = {rv.x, rv.y, rv.z, rv.w};
        const float ii[4] = {iv.x, iv.y, iv.z, iv.w};
        const float uu[4] = {uv.x, uv.y, uv.z, uv.w};
        const float ll[4] = {lf.x, lf.y, lf.z, lf.w};
        float lr[4];
        #pragma unroll
        for (int j = 0; j < 4; ++j) {
            const float a = __expf(kh[j] * rr[j]);
            const float beta = sqrtf(fmaxf(1.f - a * a, 1e-12f));
            hs[j] = a * hs[j] + beta * ii[j] * uu[j];
            lr[j] = ll[j] * hs[j];
        }
        *(uint2*)(lrb + idx) = st_bf4(lr[0], lr[1], lr[2], lr[3]);
    }
}

extern "C" void kernel_launch(void* const* d_in, const int* in_sizes, int n_in,
                              void* d_out, int out_size, void* d_ws, size_t ws_size,
                              hipStream_t stream)
{
    const float* x   = (const float*)d_in[0];
    const float* Wl  = (const float*)d_in[1];
    const float* bl  = (const float*)d_in[2];
    const float* Wr  = (const float*)d_in[3];
    const float* br  = (const float*)d_in[4];
    const float* cw  = (const float*)d_in[5];
    const float* cb  = (const float*)d_in[6];
    const float* Wa  = (const float*)d_in[7];
    const float* ba  = (const float*)d_in[8];
    const float* Wi  = (const float*)d_in[9];
    const float* bi  = (const float*)d_in[10];
    const float* lam = (const float*)d_in[11];
    const float* Wo  = (const float*)d_in[12];
    const float* bo  = (const float*)d_in[13];
    float* out = (float*)d_out;
    (void)in_sizes; (void)n_in; (void)out_size;

    const size_t wWlr = (size_t)2 * H_ * D_ * 2;   // 20.97 MB
    const size_t wWai = (size_t)2 * H_ * H_ * 2;   // 26.21 MB
    const size_t wWo  = (size_t)O_ * H_ * 2;       // 10.49 MB
    auto al = [](size_t b) { return (b + 255) & ~(size_t)255; };

    // choose batch-chunking so workspace fits: nchunk in {1,2,4}
    int nchunk = 4;
    for (int n = 1; n <= 4; n *= 2) {
        const size_t Mc = M_ / n;
        const size_t Bc = Mc / S_;
        const size_t need = al(wWlr) + al(wWai) + al(wWo)
                          + 4 * al(Mc * H_ * 2)
                          + 2 * al(Bc * NCH * H_ * 4);
        if (need <= ws_size) { nchunk = n; break; }
    }
    const int Mc = M_ / nchunk;
    const int Bc = Mc / S_;
    const size_t actB = (size_t)Mc * H_ * 2;

    char* p = (char*)d_ws;
    size_t off = 0;
    auto alloc = [&](size_t bytes) -> void* {
        void* q = p + off;
        off += al(bytes);
        return q;
    };
    unsigned short* WlrT  = (unsigned short*)alloc(wWlr);
    unsigned short* WaiT  = (unsigned short*)alloc(wWai);
    unsigned short* WoT   = (unsigned short*)alloc(wWo);
    unsigned short* slotX = (unsigned short*)alloc(actB);  // xb -> rgate -> lr
    unsigned short* slotL = (unsigned short*)alloc(actB);  // left
    unsigned short* slotR = (unsigned short*)alloc(actB);  // rin -> igate
    unsigned short* slotU = (unsigned short*)alloc(actB);  // u
    float* Asum = (float*)alloc((size_t)Bc * NCH * H_ * 4);
    float* Hend = (float*)alloc((size_t)Bc * NCH * H_ * 4);

    // weight transposes (one merged launch; z selects the weight)
    transpose_all_kernel<<<dim3(40, 40, 5), dim3(256), 0, stream>>>(
        Wl, Wr, Wa, Wi, Wo, WlrT, WaiT, WoT);

    for (int c = 0; c < nchunk; ++c) {
        const float* xc = x + (size_t)c * Mc * D_;
        float* outc = out + (size_t)c * Mc * O_;
        unsigned short* xb    = slotX;
        unsigned short* leftb = slotL;
        unsigned short* rinb  = slotR;
        unsigned short* ub    = slotU;
        unsigned short* rgb   = slotX;   // xb dead after GEMM1
        unsigned short* igb   = slotR;   // rinb dead after conv
        unsigned short* lrb   = slotX;   // in-place over rgate in pass 3

        cast_x_kernel<<<dim3(Mc*D_/4/256), dim3(256), 0, stream>>>(xc, xb, Mc*D_/4);
        gemm_kernel<0><<<dim3((2*H_)/128, Mc/128), dim3(256), 0, stream>>>(xb, WlrT, D_, bl, br, leftb, rinb);
        conv_kernel<<<dim3(Bc*S_*H_/16/256), dim3(256), 0, stream>>>(rinb, cw, cb, ub);
        gemm_kernel<1><<<dim3((2*H_)/128, Mc/128), dim3(256), 0, stream>>>(ub, WaiT, H_, ba, bi, rgb, igb);
        scan_pass1<<<dim3(Bc*NCH*(H_/4)/256), dim3(256), 0, stream>>>(rgb, igb, ub, lam, Asum, Hend);
        {
            const int n2 = Bc * (H_/4);
            scan_pass2<<<dim3((n2 + 255)/256), dim3(256), 0, stream>>>(Asum, Hend, n2);
        }
        scan_pass3<<<dim3(Bc*NCH*(H_/4)/256), dim3(256), 0, stream>>>(rgb, igb, ub, leftb, lam, Hend, lrb);
        gemm_kernel<2><<<dim3(O_/128, Mc/128), dim3(256), 0, stream>>>(lrb, WoT, H_, bo, nullptr, outc, nullptr);
    }
}